// Round 3
// baseline (212.881 us; speedup 1.0000x reference)
//
#include <hip/hip_runtime.h>

#pragma clang fp contract(off)

#define B_   512
#define N_   16384
#define A_   64
#define TPB  1024
#define NW   16              // waves per block
#define CAP  2048

#define AS1 __attribute__((address_space(1)))
#define AS3 __attribute__((address_space(3)))

// async global->LDS, 16 B per lane (HW: wave-uniform LDS base + lane*16).
__device__ __forceinline__ void gl2lds16(const float* g, float* l) {
    __builtin_amdgcn_global_load_lds((const AS1 unsigned int*)g,
                                     (AS3 unsigned int*)l, 16, 0, 0);
}

// One block per batch. Phase A is BARRIER-FREE: each wave streams its private
// 1024-element segment through wave-private double-buffered LDS (4 sub-chunks
// of 256 elems; 3 KB pos + 1 KB mask each, all via global_load_lds), waiting
// only on its OWN vmcnt/lgkmcnt. Tests the theory that the round-0/2 ~77 us
// plateau is block-lockstep-induced BW loss (rounds 0 vs 2 differed 100x in
// pipeline depth, timed identically -> parallelism was not the limiter).
// Cost: 151 KB LDS -> 1 block/CU (16 waves), accepted for the experiment.
__global__ __launch_bounds__(TPB) void fused_kernel(
    const float* __restrict__ pos,   const float* __restrict__ mask,
    const float* __restrict__ apos,  const float* __restrict__ amask,
    const int*   __restrict__ topk_ptr,
    float* __restrict__ out0, float* __restrict__ out1)
{
#pragma clang fp contract(off)
    __shared__ __align__(16) float wbuf[NW][2][1024]; // 128 KB wave-private stage
    __shared__ unsigned       hist[2048];             // 8 KB 11-bit histogram
    __shared__ unsigned       hist2[32];              // 5-bit refinement
    __shared__ unsigned       cand_bits[CAP];
    __shared__ unsigned short cand_idx[CAP];
    __shared__ unsigned char  sel_flags[CAP];
    __shared__ float          s_atoms[A_ * 3 + A_];   // 192 pos + 64 mask
    __shared__ unsigned s_B11, s_less11, s_P16, s_j, s_ncand, s_k;

    const int tid = threadIdx.x;
    const int w   = tid >> 6;        // wave id 0..15
    const int l   = tid & 63;        // lane id
    const int b   = blockIdx.x;
    const float* __restrict__ p = pos  + (size_t)b * N_ * 3;
    const float* __restrict__ m = mask + (size_t)b * N_;

    // ---- init: zero hists, stage atoms coalesced, load k ------------------
    hist[tid]        = 0u;
    hist[tid + 1024] = 0u;
    if (tid < 32) hist2[tid] = 0u;
    if (tid < 256)
        s_atoms[tid] = (tid < 192) ? apos[(size_t)b * 192 + tid]
                                   : amask[(size_t)b * 64 + (tid - 192)];
    if (tid == 0) {
        s_ncand = 0u;
        int kk = *topk_ptr;
        if (kk < 0)  kk = 0;
        if (kk > N_) kk = N_;
        s_k = (unsigned)kk;
    }
    __syncthreads();   // only block-wide sync before Phase A ends

    // per-wave sub-chunk stager: sub s covers elems [w*1024+s*256, +256)
#define ISSUE_SUB(S, BUFIDX) do {                                          \
        const float* ps_ = p + (size_t)(w * 1024 + (S) * 256) * 3;         \
        float* dst_ = &wbuf[w][(BUFIDX)][0];                               \
        gl2lds16(ps_ + 4 * l,        dst_ + 4 * l);                        \
        gl2lds16(ps_ + 256 + 4 * l,  dst_ + 256 + 4 * l);                  \
        gl2lds16(ps_ + 512 + 4 * l,  dst_ + 512 + 4 * l);                  \
        gl2lds16(m + w * 1024 + (S) * 256 + 4 * l, dst_ + 768 + 4 * l);    \
    } while (0)

    // ---- issue subs 0,1 now; they fly while the centroid runs -------------
    ISSUE_SUB(0, 0);
    ISSUE_SUB(1, 1);

    // ---- centroid, PER-WAVE (identical arithmetic in every wave ->
    //      bit-exact, no cross-wave broadcast barrier needed) ---------------
    float cx, cy, cz;
    {
        float comp = 0.0f, ms = 0.0f;
        if (l < 3) {
            comp = s_atoms[l];
            for (int a = 1; a < A_; ++a) comp += s_atoms[a * 3 + l];
        }
        if (l == 3) {
            const float* am = s_atoms + 192;
            float r0 = am[0], r1 = am[1], r2 = am[2], r3 = am[3];
            float r4 = am[4], r5 = am[5], r6 = am[6], r7 = am[7];
            for (int i = 8; i < A_; i += 8) {
                r0 += am[i + 0]; r1 += am[i + 1]; r2 += am[i + 2]; r3 += am[i + 3];
                r4 += am[i + 4]; r5 += am[i + 5]; r6 += am[i + 6]; r7 += am[i + 7];
            }
            ms = ((r0 + r1) + (r2 + r3)) + ((r4 + r5) + (r6 + r7));
        }
        ms = __shfl(ms, 3, 64);
        const float cc = (l < 3) ? comp / ms : 0.0f;  // correctly-rounded div
        cx = __shfl(cc, 0, 64);
        cy = __shfl(cc, 1, 64);
        cz = __shfl(cc, 2, 64);
    }

    const unsigned k = s_k;

    // ---- Phase A: barrier-free per-wave streaming -------------------------
    unsigned rbits[16];
    float    rmv[16];

#define DO_ELEM(S, J, PX, PY, PZ, MM) do {                                 \
        float dx_ = cx - (PX), dy_ = cy - (PY), dz_ = cz - (PZ);           \
        float s_ = (dx_ * dx_ + dy_ * dy_) + dz_ * dz_;                    \
        s_ = s_ + 1e-12f;                                                  \
        float d_ = sqrtf(s_);                                              \
        d_ = d_ + (1.0f - (MM)) * 1e10f;                                   \
        const unsigned bits_ = __float_as_uint(d_);                        \
        rbits[(S) * 4 + (J)] = bits_;                                      \
        rmv[(S) * 4 + (J)]   = (MM);                                       \
        atomicAdd(&hist[bits_ >> 21], 1u);                                 \
    } while (0)

#pragma unroll
    for (int s = 0; s < 4; ++s) {
        // my sub-s loads (4 ops) done when only sub-(s+1)'s 4 remain
        if (s < 3) asm volatile("s_waitcnt vmcnt(4)" ::: "memory");
        else       asm volatile("s_waitcnt vmcnt(0)" ::: "memory");
        __builtin_amdgcn_sched_barrier(0);

        const float* buf = &wbuf[w][s & 1][0];
        const float4 q0 = *(const float4*)(buf + 12 * l);       // 48 B/lane
        const float4 q1 = *(const float4*)(buf + 12 * l + 4);
        const float4 q2 = *(const float4*)(buf + 12 * l + 8);
        const float4 mv = *(const float4*)(buf + 768 + 4 * l);

        DO_ELEM(s, 0, q0.x, q0.y, q0.z, mv.x);
        DO_ELEM(s, 1, q0.w, q1.x, q1.y, mv.y);
        DO_ELEM(s, 2, q1.z, q1.w, q2.x, mv.z);
        DO_ELEM(s, 3, q2.y, q2.z, q2.w, mv.w);

        // my LDS reads complete before overwriting this buffer
        asm volatile("s_waitcnt lgkmcnt(0)" ::: "memory");
        __builtin_amdgcn_sched_barrier(0);
        if (s + 2 < 4) ISSUE_SUB(s + 2, s & 1);
    }
    __syncthreads();

    if (k > 0) {
        // ---- Phase B: wave-0 shuffle scan finds the 11-bit bucket ---------
        if (tid < 64) {
            unsigned s = 0;
#pragma unroll
            for (int i = 0; i < 32; ++i) s += hist[tid * 32 + i];
            unsigned incl = s;
#pragma unroll
            for (int off = 1; off < 64; off <<= 1) {
                unsigned v = (unsigned)__shfl_up((int)incl, off, 64);
                if (tid >= off) incl += v;
            }
            unsigned long long bal = __ballot(incl >= k);
            const int g = __ffsll(bal) - 1;
            const unsigned cum1 = (unsigned)__shfl((int)(incl - s), g, 64);

            unsigned h2 = (tid < 32) ? hist[g * 32 + tid] : 0u;
            unsigned incl2 = h2;
#pragma unroll
            for (int off = 1; off < 64; off <<= 1) {
                unsigned v = (unsigned)__shfl_up((int)incl2, off, 64);
                if (tid >= off) incl2 += v;
            }
            unsigned long long bal2 = __ballot(tid < 32 && (cum1 + incl2 >= k));
            const int sb = __ffsll(bal2) - 1;
            const unsigned cum2 = cum1 + (unsigned)__shfl((int)(incl2 - h2), sb, 64);
            if (tid == 0) { s_B11 = (unsigned)(g * 32 + sb); s_less11 = cum2; }
        }
        __syncthreads();
        const unsigned B11 = s_B11;

        // ---- Phase C: refine low-5 bits (from registers) ------------------
#pragma unroll
        for (int x = 0; x < 16; ++x) {
            const unsigned v = rbits[x] >> 16;
            if ((v >> 5) == B11) atomicAdd(&hist2[v & 31u], 1u);
        }
        __syncthreads();
        if (tid < 64) {
            unsigned h = (tid < 32) ? hist2[tid] : 0u;
            unsigned incl = h;
#pragma unroll
            for (int off = 1; off < 64; off <<= 1) {
                unsigned v = (unsigned)__shfl_up((int)incl, off, 64);
                if (tid >= off) incl += v;
            }
            const unsigned less11 = s_less11;
            unsigned long long bal = __ballot(tid < 32 && (less11 + incl >= k));
            const int sb = __ffsll(bal) - 1;
            const unsigned cumx = less11 + (unsigned)__shfl((int)(incl - h), sb, 64);
            if (tid == 0) { s_P16 = (B11 << 5) | (unsigned)sb; s_j = k - cumx; }
        }
        __syncthreads();
        const unsigned P16 = s_P16;
        const unsigned j   = s_j;

        // ---- Phase D: gather boundary candidates; mark slot in-register ---
        // bits16 can never be 0xFFFF (d >= 0 finite), so it's a safe marker.
#pragma unroll
        for (int x = 0; x < 16; ++x) {
            const unsigned bits = rbits[x];
            if ((bits >> 16) == P16) {
                const unsigned wr = atomicAdd(&s_ncand, 1u);
                if (wr < CAP) {
                    cand_bits[wr] = bits;
                    cand_idx[wr]  = (unsigned short)(w * 1024 + (x >> 2) * 256
                                                     + 4 * l + (x & 3));
                    rbits[x] = 0xFFFF0000u | wr;
                }
            }
        }
        __syncthreads();

        // ---- Phase E: rank candidates (tie -> lowest index) -> flags ------
        const unsigned cnum = min(s_ncand, (unsigned)CAP);
        for (unsigned t = tid; t < cnum; t += TPB) {
            const unsigned bt = cand_bits[t];
            const unsigned it = cand_idx[t];
            unsigned rank = 0;
            for (unsigned u = 0; u < cnum; ++u) {
                const unsigned bu = cand_bits[u];
                rank += (bu < bt) || (bu == bt && (unsigned)cand_idx[u] < it);
            }
            sel_flags[t] = (rank < j) ? (unsigned char)1 : (unsigned char)0;
        }
        __syncthreads();
    }

    // ---- Phase F: write both masks, float4 stores -------------------------
    const unsigned P16f = (k > 0) ? s_P16 : 0u;
#pragma unroll
    for (int s = 0; s < 4; ++s) {
        float4 o0, o1;
        float* o0p = &o0.x; float* o1p = &o1.x;
#pragma unroll
        for (int jj = 0; jj < 4; ++jj) {
            const unsigned v   = rbits[s * 4 + jj];
            const unsigned v16 = v >> 16;
            bool sel = false;
            if (k > 0) {
                sel = (v16 == 0xFFFFu) ? (sel_flags[v & (CAP - 1u)] != 0)
                                       : (v16 < P16f);
            }
            const float mvv = rmv[s * 4 + jj];
            o0p[jj] = sel ? 0.0f  : mvv;
            o1p[jj] = sel ? 32.0f : (1.0f - mvv);
        }
        const size_t o = (size_t)b * N_ + w * 1024 + s * 256 + 4 * l;
        *(float4*)(out0 + o) = o0;
        *(float4*)(out1 + o) = o1;
    }
}

extern "C" void kernel_launch(void* const* d_in, const int* in_sizes, int n_in,
                              void* d_out, int out_size, void* d_ws, size_t ws_size,
                              hipStream_t stream) {
    const float* pos   = (const float*)d_in[0];   // [B,N,3]
    const float* rmask = (const float*)d_in[1];   // [B,N]
    const float* apos  = (const float*)d_in[2];   // [B,A,3]
    const float* amask = (const float*)d_in[3];   // [B,A]
    // d_in[4] = max_p (unused by the reference outputs)
    const int*   topk  = (const int*)d_in[5];

    float* out0 = (float*)d_out;
    float* out1 = out0 + (size_t)B_ * N_;

    fused_kernel<<<B_, TPB, 0, stream>>>(pos, rmask, apos, amask, topk, out0, out1);
}

// Round 4
// 212.278 us; speedup vs baseline: 1.0028x; 1.0028x over previous
//
#include <hip/hip_runtime.h>

#pragma clang fp contract(off)

#define B_   512
#define N_   16384
#define A_   64
#define TPB  1024
#define NW   16              // waves per block
#define CAP  2048

#define AS1 __attribute__((address_space(1)))
#define AS3 __attribute__((address_space(3)))

typedef float f32x4 __attribute__((ext_vector_type(4)));

// async global->LDS, 16 B per lane (HW: wave-uniform LDS base + lane*16).
__device__ __forceinline__ void gl2lds16(const float* g, float* l) {
    __builtin_amdgcn_global_load_lds((const AS1 unsigned int*)g,
                                     (AS3 unsigned int*)l, 16, 0, 0);
}

// One block per batch. Identical to round 3 EXCEPT Phase F: output stores are
// nontemporal (global_store_dwordx4 nt) to bypass HBM write-allocate.
// Single-variable A/B: rounds 0/2/3 all showed FETCH_SIZE ~= WRITE_SIZE
// ~= 64 MiB (= the outputs, NOT the 134 MB inputs) -> suspected allocate-
// on-store doubling HBM demand while inputs ride the L3.
__global__ __launch_bounds__(TPB) void fused_kernel(
    const float* __restrict__ pos,   const float* __restrict__ mask,
    const float* __restrict__ apos,  const float* __restrict__ amask,
    const int*   __restrict__ topk_ptr,
    float* __restrict__ out0, float* __restrict__ out1)
{
#pragma clang fp contract(off)
    __shared__ __align__(16) float wbuf[NW][2][1024]; // 128 KB wave-private stage
    __shared__ unsigned       hist[2048];             // 8 KB 11-bit histogram
    __shared__ unsigned       hist2[32];              // 5-bit refinement
    __shared__ unsigned       cand_bits[CAP];
    __shared__ unsigned short cand_idx[CAP];
    __shared__ unsigned char  sel_flags[CAP];
    __shared__ float          s_atoms[A_ * 3 + A_];   // 192 pos + 64 mask
    __shared__ unsigned s_B11, s_less11, s_P16, s_j, s_ncand, s_k;

    const int tid = threadIdx.x;
    const int w   = tid >> 6;        // wave id 0..15
    const int l   = tid & 63;        // lane id
    const int b   = blockIdx.x;
    const float* __restrict__ p = pos  + (size_t)b * N_ * 3;
    const float* __restrict__ m = mask + (size_t)b * N_;

    // ---- init: zero hists, stage atoms coalesced, load k ------------------
    hist[tid]        = 0u;
    hist[tid + 1024] = 0u;
    if (tid < 32) hist2[tid] = 0u;
    if (tid < 256)
        s_atoms[tid] = (tid < 192) ? apos[(size_t)b * 192 + tid]
                                   : amask[(size_t)b * 64 + (tid - 192)];
    if (tid == 0) {
        s_ncand = 0u;
        int kk = *topk_ptr;
        if (kk < 0)  kk = 0;
        if (kk > N_) kk = N_;
        s_k = (unsigned)kk;
    }
    __syncthreads();   // only block-wide sync before Phase A ends

    // per-wave sub-chunk stager: sub s covers elems [w*1024+s*256, +256)
#define ISSUE_SUB(S, BUFIDX) do {                                          \
        const float* ps_ = p + (size_t)(w * 1024 + (S) * 256) * 3;         \
        float* dst_ = &wbuf[w][(BUFIDX)][0];                               \
        gl2lds16(ps_ + 4 * l,        dst_ + 4 * l);                        \
        gl2lds16(ps_ + 256 + 4 * l,  dst_ + 256 + 4 * l);                  \
        gl2lds16(ps_ + 512 + 4 * l,  dst_ + 512 + 4 * l);                  \
        gl2lds16(m + w * 1024 + (S) * 256 + 4 * l, dst_ + 768 + 4 * l);    \
    } while (0)

    // ---- issue subs 0,1 now; they fly while the centroid runs -------------
    ISSUE_SUB(0, 0);
    ISSUE_SUB(1, 1);

    // ---- centroid, PER-WAVE (identical arithmetic in every wave ->
    //      bit-exact, no cross-wave broadcast barrier needed) ---------------
    float cx, cy, cz;
    {
        float comp = 0.0f, ms = 0.0f;
        if (l < 3) {
            comp = s_atoms[l];
            for (int a = 1; a < A_; ++a) comp += s_atoms[a * 3 + l];
        }
        if (l == 3) {
            const float* am = s_atoms + 192;
            float r0 = am[0], r1 = am[1], r2 = am[2], r3 = am[3];
            float r4 = am[4], r5 = am[5], r6 = am[6], r7 = am[7];
            for (int i = 8; i < A_; i += 8) {
                r0 += am[i + 0]; r1 += am[i + 1]; r2 += am[i + 2]; r3 += am[i + 3];
                r4 += am[i + 4]; r5 += am[i + 5]; r6 += am[i + 6]; r7 += am[i + 7];
            }
            ms = ((r0 + r1) + (r2 + r3)) + ((r4 + r5) + (r6 + r7));
        }
        ms = __shfl(ms, 3, 64);
        const float cc = (l < 3) ? comp / ms : 0.0f;  // correctly-rounded div
        cx = __shfl(cc, 0, 64);
        cy = __shfl(cc, 1, 64);
        cz = __shfl(cc, 2, 64);
    }

    const unsigned k = s_k;

    // ---- Phase A: barrier-free per-wave streaming -------------------------
    unsigned rbits[16];
    float    rmv[16];

#define DO_ELEM(S, J, PX, PY, PZ, MM) do {                                 \
        float dx_ = cx - (PX), dy_ = cy - (PY), dz_ = cz - (PZ);           \
        float s_ = (dx_ * dx_ + dy_ * dy_) + dz_ * dz_;                    \
        s_ = s_ + 1e-12f;                                                  \
        float d_ = sqrtf(s_);                                              \
        d_ = d_ + (1.0f - (MM)) * 1e10f;                                   \
        const unsigned bits_ = __float_as_uint(d_);                        \
        rbits[(S) * 4 + (J)] = bits_;                                      \
        rmv[(S) * 4 + (J)]   = (MM);                                       \
        atomicAdd(&hist[bits_ >> 21], 1u);                                 \
    } while (0)

#pragma unroll
    for (int s = 0; s < 4; ++s) {
        // my sub-s loads (4 ops) done when only sub-(s+1)'s 4 remain
        if (s < 3) asm volatile("s_waitcnt vmcnt(4)" ::: "memory");
        else       asm volatile("s_waitcnt vmcnt(0)" ::: "memory");
        __builtin_amdgcn_sched_barrier(0);

        const float* buf = &wbuf[w][s & 1][0];
        const float4 q0 = *(const float4*)(buf + 12 * l);       // 48 B/lane
        const float4 q1 = *(const float4*)(buf + 12 * l + 4);
        const float4 q2 = *(const float4*)(buf + 12 * l + 8);
        const float4 mv = *(const float4*)(buf + 768 + 4 * l);

        DO_ELEM(s, 0, q0.x, q0.y, q0.z, mv.x);
        DO_ELEM(s, 1, q0.w, q1.x, q1.y, mv.y);
        DO_ELEM(s, 2, q1.z, q1.w, q2.x, mv.z);
        DO_ELEM(s, 3, q2.y, q2.z, q2.w, mv.w);

        // my LDS reads complete before overwriting this buffer
        asm volatile("s_waitcnt lgkmcnt(0)" ::: "memory");
        __builtin_amdgcn_sched_barrier(0);
        if (s + 2 < 4) ISSUE_SUB(s + 2, s & 1);
    }
    __syncthreads();

    if (k > 0) {
        // ---- Phase B: wave-0 shuffle scan finds the 11-bit bucket ---------
        if (tid < 64) {
            unsigned s = 0;
#pragma unroll
            for (int i = 0; i < 32; ++i) s += hist[tid * 32 + i];
            unsigned incl = s;
#pragma unroll
            for (int off = 1; off < 64; off <<= 1) {
                unsigned v = (unsigned)__shfl_up((int)incl, off, 64);
                if (tid >= off) incl += v;
            }
            unsigned long long bal = __ballot(incl >= k);
            const int g = __ffsll(bal) - 1;
            const unsigned cum1 = (unsigned)__shfl((int)(incl - s), g, 64);

            unsigned h2 = (tid < 32) ? hist[g * 32 + tid] : 0u;
            unsigned incl2 = h2;
#pragma unroll
            for (int off = 1; off < 64; off <<= 1) {
                unsigned v = (unsigned)__shfl_up((int)incl2, off, 64);
                if (tid >= off) incl2 += v;
            }
            unsigned long long bal2 = __ballot(tid < 32 && (cum1 + incl2 >= k));
            const int sb = __ffsll(bal2) - 1;
            const unsigned cum2 = cum1 + (unsigned)__shfl((int)(incl2 - h2), sb, 64);
            if (tid == 0) { s_B11 = (unsigned)(g * 32 + sb); s_less11 = cum2; }
        }
        __syncthreads();
        const unsigned B11 = s_B11;

        // ---- Phase C: refine low-5 bits (from registers) ------------------
#pragma unroll
        for (int x = 0; x < 16; ++x) {
            const unsigned v = rbits[x] >> 16;
            if ((v >> 5) == B11) atomicAdd(&hist2[v & 31u], 1u);
        }
        __syncthreads();
        if (tid < 64) {
            unsigned h = (tid < 32) ? hist2[tid] : 0u;
            unsigned incl = h;
#pragma unroll
            for (int off = 1; off < 64; off <<= 1) {
                unsigned v = (unsigned)__shfl_up((int)incl, off, 64);
                if (tid >= off) incl += v;
            }
            const unsigned less11 = s_less11;
            unsigned long long bal = __ballot(tid < 32 && (less11 + incl >= k));
            const int sb = __ffsll(bal) - 1;
            const unsigned cumx = less11 + (unsigned)__shfl((int)(incl - h), sb, 64);
            if (tid == 0) { s_P16 = (B11 << 5) | (unsigned)sb; s_j = k - cumx; }
        }
        __syncthreads();
        const unsigned P16 = s_P16;
        const unsigned j   = s_j;

        // ---- Phase D: gather boundary candidates; mark slot in-register ---
        // bits16 can never be 0xFFFF (d >= 0 finite), so it's a safe marker.
#pragma unroll
        for (int x = 0; x < 16; ++x) {
            const unsigned bits = rbits[x];
            if ((bits >> 16) == P16) {
                const unsigned wr = atomicAdd(&s_ncand, 1u);
                if (wr < CAP) {
                    cand_bits[wr] = bits;
                    cand_idx[wr]  = (unsigned short)(w * 1024 + (x >> 2) * 256
                                                     + 4 * l + (x & 3));
                    rbits[x] = 0xFFFF0000u | wr;
                }
            }
        }
        __syncthreads();

        // ---- Phase E: rank candidates (tie -> lowest index) -> flags ------
        const unsigned cnum = min(s_ncand, (unsigned)CAP);
        for (unsigned t = tid; t < cnum; t += TPB) {
            const unsigned bt = cand_bits[t];
            const unsigned it = cand_idx[t];
            unsigned rank = 0;
            for (unsigned u = 0; u < cnum; ++u) {
                const unsigned bu = cand_bits[u];
                rank += (bu < bt) || (bu == bt && (unsigned)cand_idx[u] < it);
            }
            sel_flags[t] = (rank < j) ? (unsigned char)1 : (unsigned char)0;
        }
        __syncthreads();
    }

    // ---- Phase F: write both masks, NONTEMPORAL float4 stores -------------
    const unsigned P16f = (k > 0) ? s_P16 : 0u;
#pragma unroll
    for (int s = 0; s < 4; ++s) {
        f32x4 o0, o1;
#pragma unroll
        for (int jj = 0; jj < 4; ++jj) {
            const unsigned v   = rbits[s * 4 + jj];
            const unsigned v16 = v >> 16;
            bool sel = false;
            if (k > 0) {
                sel = (v16 == 0xFFFFu) ? (sel_flags[v & (CAP - 1u)] != 0)
                                       : (v16 < P16f);
            }
            const float mvv = rmv[s * 4 + jj];
            o0[jj] = sel ? 0.0f  : mvv;
            o1[jj] = sel ? 32.0f : (1.0f - mvv);
        }
        const size_t o = (size_t)b * N_ + w * 1024 + s * 256 + 4 * l;
        __builtin_nontemporal_store(o0, (f32x4*)(out0 + o));
        __builtin_nontemporal_store(o1, (f32x4*)(out1 + o));
    }
}

extern "C" void kernel_launch(void* const* d_in, const int* in_sizes, int n_in,
                              void* d_out, int out_size, void* d_ws, size_t ws_size,
                              hipStream_t stream) {
    const float* pos   = (const float*)d_in[0];   // [B,N,3]
    const float* rmask = (const float*)d_in[1];   // [B,N]
    const float* apos  = (const float*)d_in[2];   // [B,A,3]
    const float* amask = (const float*)d_in[3];   // [B,A]
    // d_in[4] = max_p (unused by the reference outputs)
    const int*   topk  = (const int*)d_in[5];

    float* out0 = (float*)d_out;
    float* out1 = out0 + (size_t)B_ * N_;

    fused_kernel<<<B_, TPB, 0, stream>>>(pos, rmask, apos, amask, topk, out0, out1);
}

// Round 5
// 212.097 us; speedup vs baseline: 1.0037x; 1.0009x over previous
//
#include <hip/hip_runtime.h>

#pragma clang fp contract(off)

#define B_   512
#define N_   16384
#define A_   64
#define TPB  1024
#define CAP  2048
#define STAGE_F 32768        // floats: 24576 pos + 8192 mask (8192 elems)

#define AS1 __attribute__((address_space(1)))
#define AS3 __attribute__((address_space(3)))

// async global->LDS, 16 B per lane (wave-uniform LDS base + lane*16).
__device__ __forceinline__ void gl2lds16(const float* g, float* l) {
    __builtin_amdgcn_global_load_lds((const AS1 unsigned int*)g,
                                     (AS3 unsigned int*)l, 16, 0, 0);
}

// barrier that does NOT drain vmcnt: in-flight global_load_lds prefetch
// survives the serial selection phases (counted-vmcnt discipline).
#define RAWBAR() do { asm volatile("s_waitcnt lgkmcnt(0)" ::: "memory"); \
                      __builtin_amdgcn_s_barrier();                      \
                      asm volatile("" ::: "memory"); } while (0)

// per-wave centroid, bit-exact numpy order (identical in every wave).
__device__ __forceinline__ void centroid_wave(const float* sa, const int l,
                                              float& cx, float& cy, float& cz) {
    float comp = 0.0f, ms = 0.0f;
    if (l < 3) {
        comp = sa[l];
        for (int a = 1; a < A_; ++a) comp += sa[a * 3 + l];
    }
    if (l == 3) {
        const float* am = sa + 192;
        float r0 = am[0], r1 = am[1], r2 = am[2], r3 = am[3];
        float r4 = am[4], r5 = am[5], r6 = am[6], r7 = am[7];
        for (int i = 8; i < A_; i += 8) {
            r0 += am[i + 0]; r1 += am[i + 1]; r2 += am[i + 2]; r3 += am[i + 3];
            r4 += am[i + 4]; r5 += am[i + 5]; r6 += am[i + 6]; r7 += am[i + 7];
        }
        ms = ((r0 + r1) + (r2 + r3)) + ((r4 + r5) + (r6 + r7));
    }
    ms = __shfl(ms, 3, 64);
    const float cc = (l < 3) ? comp / ms : 0.0f;   // correctly-rounded divide
    cx = __shfl(cc, 0, 64);
    cy = __shfl(cc, 1, 64);
    cz = __shfl(cc, 2, 64);
}

// Phases B..E (exact top-k boundary select + candidate rank). All barriers
// are RAWBAR (lgkm-only) so outstanding prefetch loads keep flying.
// Returns P16 (0 when k==0). Marks boundary-selected elems in rbits.
__device__ __forceinline__ unsigned run_select(
    unsigned (&rbits)[16], const unsigned k, const int tid,
    unsigned* hist, unsigned* hist2, unsigned* cand_bits,
    unsigned short* cand_idx, unsigned char* sel_flags,
    unsigned* s_B11, unsigned* s_less11, unsigned* s_P16, unsigned* s_j,
    unsigned* s_ncand)
{
    if (k == 0) return 0u;
    // ---- Phase B: wave-0 shuffle scan finds the 11-bit bucket -------------
    if (tid < 64) {
        unsigned s = 0;
#pragma unroll
        for (int i = 0; i < 32; ++i) s += hist[tid * 32 + i];
        unsigned incl = s;
#pragma unroll
        for (int off = 1; off < 64; off <<= 1) {
            unsigned v = (unsigned)__shfl_up((int)incl, off, 64);
            if (tid >= off) incl += v;
        }
        unsigned long long bal = __ballot(incl >= k);
        const int g = __ffsll(bal) - 1;
        const unsigned cum1 = (unsigned)__shfl((int)(incl - s), g, 64);

        unsigned h2 = (tid < 32) ? hist[g * 32 + tid] : 0u;
        unsigned incl2 = h2;
#pragma unroll
        for (int off = 1; off < 64; off <<= 1) {
            unsigned v = (unsigned)__shfl_up((int)incl2, off, 64);
            if (tid >= off) incl2 += v;
        }
        unsigned long long bal2 = __ballot(tid < 32 && (cum1 + incl2 >= k));
        const int sb = __ffsll(bal2) - 1;
        const unsigned cum2 = cum1 + (unsigned)__shfl((int)(incl2 - h2), sb, 64);
        if (tid == 0) { *s_B11 = (unsigned)(g * 32 + sb); *s_less11 = cum2; }
    }
    RAWBAR();
    const unsigned B11 = *s_B11;

    // ---- Phase C: refine low-5 bits (from registers) ----------------------
#pragma unroll
    for (int x = 0; x < 16; ++x) {
        const unsigned v = rbits[x] >> 16;
        if ((v >> 5) == B11) atomicAdd(&hist2[v & 31u], 1u);
    }
    RAWBAR();
    if (tid < 64) {
        unsigned h = (tid < 32) ? hist2[tid] : 0u;
        unsigned incl = h;
#pragma unroll
        for (int off = 1; off < 64; off <<= 1) {
            unsigned v = (unsigned)__shfl_up((int)incl, off, 64);
            if (tid >= off) incl += v;
        }
        const unsigned less11 = *s_less11;
        unsigned long long bal = __ballot(tid < 32 && (less11 + incl >= k));
        const int sb = __ffsll(bal) - 1;
        const unsigned cumx = less11 + (unsigned)__shfl((int)(incl - h), sb, 64);
        if (tid == 0) { *s_P16 = (B11 << 5) | (unsigned)sb; *s_j = k - cumx; }
    }
    RAWBAR();
    const unsigned P16 = *s_P16;
    const unsigned j   = *s_j;

    // ---- Phase D: gather boundary candidates; mark slot in-register -------
    // bits16 can never be 0xFFFF (d >= 0 finite), so it's a safe marker.
#pragma unroll
    for (int x = 0; x < 16; ++x) {
        const unsigned bits = rbits[x];
        if ((bits >> 16) == P16) {
            const unsigned wr = atomicAdd(s_ncand, 1u);
            if (wr < CAP) {
                cand_bits[wr] = bits;
                cand_idx[wr]  = (unsigned short)((x >> 2) * 4096 + tid * 4 + (x & 3));
                rbits[x] = 0xFFFF0000u | wr;
            }
        }
    }
    RAWBAR();

    // ---- Phase E: rank candidates (tie -> lowest index) -> flags ----------
    const unsigned cnum = min(*s_ncand, (unsigned)CAP);
    for (unsigned t = tid; t < cnum; t += TPB) {
        const unsigned bt = cand_bits[t];
        const unsigned it = cand_idx[t];
        unsigned rank = 0;
        for (unsigned u = 0; u < cnum; ++u) {
            const unsigned bu = cand_bits[u];
            rank += (bu < bt) || (bu == bt && (unsigned)cand_idx[u] < it);
        }
        sel_flags[t] = (rank < j) ? (unsigned char)1 : (unsigned char)0;
    }
    RAWBAR();
    return P16;
}

// Phase F: write both masks from registers + flags (float4 stores).
__device__ __forceinline__ void write_masks(
    const unsigned (&rbits)[16], const float (&rmv)[16],
    const unsigned P16f, const unsigned k, const unsigned char* sel_flags,
    float* out0, float* out1, const size_t base, const int tid)
{
#pragma unroll
    for (int it = 0; it < 4; ++it) {
        const int i0 = it * 4096 + tid * 4;
        float4 o0, o1;
        float* o0p = &o0.x; float* o1p = &o1.x;
#pragma unroll
        for (int jj = 0; jj < 4; ++jj) {
            const unsigned v   = rbits[it * 4 + jj];
            const unsigned v16 = v >> 16;
            bool sel = false;
            if (k > 0) {
                sel = (v16 == 0xFFFFu) ? (sel_flags[v & (CAP - 1u)] != 0)
                                       : (v16 < P16f);
            }
            const float mvv = rmv[it * 4 + jj];
            o0p[jj] = sel ? 0.0f  : mvv;
            o1p[jj] = sel ? 32.0f : (1.0f - mvv);
        }
        *(float4*)(out0 + base + i0) = o0;
        *(float4*)(out1 + base + i0) = o1;
    }
}

// Two batches per block (grid 256, 1 block/CU). The serial selection phases
// of batch 0 are overlapped with a 128 KB global_load_lds prefetch of batch
// 1's first half (counted vmcnt: no barrier drains it), and batch 0's output
// stores overlap batch 1's LDS-fed distance pass. Tests the last structural
// hypothesis: the read-burst / serial-select / write-burst phase gaps are
// the unattributed ~60% stall common to rounds 0-4.
__global__ __launch_bounds__(TPB) void fused_kernel(
    const float* __restrict__ pos,   const float* __restrict__ mask,
    const float* __restrict__ apos,  const float* __restrict__ amask,
    const int*   __restrict__ topk_ptr,
    float* __restrict__ out0, float* __restrict__ out1)
{
#pragma clang fp contract(off)
    __shared__ __align__(16) float stage[STAGE_F];  // 128 KB batch-1 prefetch
    __shared__ unsigned       hist[2048];           // 8 KB 11-bit histogram
    __shared__ unsigned       hist2[32];
    __shared__ unsigned       cand_bits[CAP];
    __shared__ unsigned short cand_idx[CAP];
    __shared__ unsigned char  sel_flags[CAP];
    __shared__ float          s_atoms[256];         // batch-0: 192 pos + 64 mask
    __shared__ __align__(16) float s_atoms2[256];   // batch-1 (DMA-filled)
    __shared__ unsigned s_B11, s_less11, s_P16, s_j, s_ncand, s_k;

    const int tid = threadIdx.x;
    const int l   = tid & 63;
    const int b0  = 2 * blockIdx.x;
    const int b1  = b0 + 1;
    const float* __restrict__ p0 = pos  + (size_t)b0 * N_ * 3;
    const float* __restrict__ m0 = mask + (size_t)b0 * N_;
    const float* __restrict__ p1 = pos  + (size_t)b1 * N_ * 3;
    const float* __restrict__ m1 = mask + (size_t)b1 * N_;

    // ---- init -------------------------------------------------------------
    hist[tid]        = 0u;
    hist[tid + 1024] = 0u;
    if (tid < 32) hist2[tid] = 0u;
    if (tid < 256)
        s_atoms[tid] = (tid < 192) ? apos[(size_t)b0 * 192 + tid]
                                   : amask[(size_t)b0 * 64 + (tid - 192)];
    if (tid == 0) {
        s_ncand = 0u;
        int kk = *topk_ptr;
        if (kk < 0)  kk = 0;
        if (kk > N_) kk = N_;
        s_k = (unsigned)kk;
    }
    __syncthreads();

    float cx, cy, cz;
    centroid_wave(s_atoms, l, cx, cy, cz);
    const unsigned k = s_k;

    unsigned rbits[16];
    float    rmv[16];

#define DO_ELEM(IT, J, PX, PY, PZ, MM) do {                                \
        float dx_ = cx - (PX), dy_ = cy - (PY), dz_ = cz - (PZ);           \
        float s2_ = (dx_ * dx_ + dy_ * dy_) + dz_ * dz_;                   \
        s2_ = s2_ + 1e-12f;                                                \
        float d_ = sqrtf(s2_);                                             \
        d_ = d_ + (1.0f - (MM)) * 1e10f;                                   \
        const unsigned bits_ = __float_as_uint(d_);                        \
        rbits[(IT) * 4 + (J)] = bits_;                                     \
        rmv[(IT) * 4 + (J)]   = (MM);                                      \
        atomicAdd(&hist[bits_ >> 21], 1u);                                 \
    } while (0)

#define DO4(IT, PA, PB, PC, MV) do {                                       \
        DO_ELEM(IT, 0, (PA).x, (PA).y, (PA).z, (MV).x);                    \
        DO_ELEM(IT, 1, (PA).w, (PB).x, (PB).y, (MV).y);                    \
        DO_ELEM(IT, 2, (PB).z, (PB).w, (PC).x, (MV).z);                    \
        DO_ELEM(IT, 3, (PC).y, (PC).z, (PC).w, (MV).w);                    \
    } while (0)

    // ---- A0: batch-0 distances, direct float4 loads -----------------------
#pragma unroll
    for (int it = 0; it < 4; ++it) {
        const int i0 = it * 4096 + tid * 4;
        const float4 pa = *(const float4*)(p0 + (size_t)i0 * 3);
        const float4 pb = *(const float4*)(p0 + (size_t)i0 * 3 + 4);
        const float4 pc = *(const float4*)(p0 + (size_t)i0 * 3 + 8);
        const float4 mv = *(const float4*)(m0 + i0);
        DO4(it, pa, pb, pc, mv);
    }

    // ---- issue batch-1 prefetch: 128 KB (first 8192 elems) + atoms --------
    // 8 gl2lds/wave; they stay in flight across ALL of B0..E0 (RAWBARs only).
#pragma unroll
    for (int q = 0; q < 8; ++q) {
        const int f = q * 4096 + tid * 4;        // float index, 16 KB per q
        const float* src = (q < 6) ? (p1 + f) : (m1 + (f - 24576));
        gl2lds16(src, &stage[f]);
    }
    if (tid < 64) {   // batch-1 atoms: one 1 KB DMA by wave 0
        const float* src = (l < 48) ? (apos + (size_t)b1 * 192 + 4 * l)
                                    : (amask + (size_t)b1 * 64 + (4 * l - 192));
        gl2lds16(src, &s_atoms2[4 * l]);
    }
    RAWBAR();   // hist0 atomics visible; prefetch NOT drained

    // ---- B0..E0 (serial select, memory busy with prefetch) ----------------
    const unsigned P16_0 = run_select(rbits, k, tid, hist, hist2, cand_bits,
                                      cand_idx, sel_flags, &s_B11, &s_less11,
                                      &s_P16, &s_j, &s_ncand);

    // ---- drain prefetch (stage + atoms2 now valid block-wide) -------------
    asm volatile("s_waitcnt vmcnt(0)" ::: "memory");
    __builtin_amdgcn_s_barrier();
    __builtin_amdgcn_sched_barrier(0);

    // ---- F0 stores (fly overlapped with batch-1 phase A) ------------------
    write_masks(rbits, rmv, P16_0, k, sel_flags, out0, out1,
                (size_t)b0 * N_, tid);

    // ---- reset selection state + batch-1 centroid -------------------------
    hist[tid]        = 0u;
    hist[tid + 1024] = 0u;
    if (tid < 32) hist2[tid] = 0u;
    if (tid == 0) s_ncand = 0u;
    centroid_wave(s_atoms2, l, cx, cy, cz);
    RAWBAR();   // zeros visible; F0 stores still in flight (not drained)

    // ---- A1: first half from LDS stage, second half direct ----------------
    {
        // issue the second-half loads first so they fly under staged compute
        const int i2 = 2 * 4096 + tid * 4;
        const int i3 = 3 * 4096 + tid * 4;
        const float4 pa2 = *(const float4*)(p1 + (size_t)i2 * 3);
        const float4 pb2 = *(const float4*)(p1 + (size_t)i2 * 3 + 4);
        const float4 pc2 = *(const float4*)(p1 + (size_t)i2 * 3 + 8);
        const float4 mv2 = *(const float4*)(m1 + i2);
        const float4 pa3 = *(const float4*)(p1 + (size_t)i3 * 3);
        const float4 pb3 = *(const float4*)(p1 + (size_t)i3 * 3 + 4);
        const float4 pc3 = *(const float4*)(p1 + (size_t)i3 * 3 + 8);
        const float4 mv3 = *(const float4*)(m1 + i3);

#pragma unroll
        for (int it = 0; it < 2; ++it) {
            const int g = it * 4096 + tid * 4;
            const float4 pa = *(const float4*)&stage[g * 3];
            const float4 pb = *(const float4*)&stage[g * 3 + 4];
            const float4 pc = *(const float4*)&stage[g * 3 + 8];
            const float4 mv = *(const float4*)&stage[24576 + g];
            DO4(it, pa, pb, pc, mv);
        }
        DO4(2, pa2, pb2, pc2, mv2);
        DO4(3, pa3, pb3, pc3, mv3);
    }
    RAWBAR();   // hist1 atomics visible

    // ---- B1..E1 + F1 ------------------------------------------------------
    const unsigned P16_1 = run_select(rbits, k, tid, hist, hist2, cand_bits,
                                      cand_idx, sel_flags, &s_B11, &s_less11,
                                      &s_P16, &s_j, &s_ncand);
    write_masks(rbits, rmv, P16_1, k, sel_flags, out0, out1,
                (size_t)b1 * N_, tid);
}

extern "C" void kernel_launch(void* const* d_in, const int* in_sizes, int n_in,
                              void* d_out, int out_size, void* d_ws, size_t ws_size,
                              hipStream_t stream) {
    const float* pos   = (const float*)d_in[0];   // [B,N,3]
    const float* rmask = (const float*)d_in[1];   // [B,N]
    const float* apos  = (const float*)d_in[2];   // [B,A,3]
    const float* amask = (const float*)d_in[3];   // [B,A]
    // d_in[4] = max_p (unused by the reference outputs)
    const int*   topk  = (const int*)d_in[5];

    float* out0 = (float*)d_out;
    float* out1 = out0 + (size_t)B_ * N_;

    fused_kernel<<<B_ / 2, TPB, 0, stream>>>(pos, rmask, apos, amask, topk,
                                             out0, out1);
}